// Round 5
// baseline (93.683 us; speedup 1.0000x reference)
//
#include <hip/hip_runtime.h>
#include <hip/hip_bf16.h>

#define H_ 256
#define W_ 256
#define C_ 128
#define NBPOS 1024   // N * 16 * 16 block positions
#define NACT 512

typedef __bf16 bf16x8 __attribute__((ext_vector_type(8)));
typedef float f32x4 __attribute__((ext_vector_type(4)));

// workspace layout (bytes)
#define SCALE_OFF 294912
#define SHIFT_OFF 295424
#define FLAGS_OFF 295936

// Fused prep: weight repack fp32 HWIO -> bf16 [tap][cin8][cout][8] (blocks 0..575),
// BN fold + flag set (block 576; flags pre-cleared via hipMemsetAsync).
__global__ void prep_kernel(const float* __restrict__ w, const float* __restrict__ b,
                            const float* __restrict__ gamma, const float* __restrict__ beta,
                            const float* __restrict__ mean, const float* __restrict__ var,
                            const int* __restrict__ active,
                            __bf16* __restrict__ wprep, float* __restrict__ scale,
                            float* __restrict__ shift, int* __restrict__ flags) {
  int blk = blockIdx.x, tid = threadIdx.x;
  if (blk < 576) {
    int o = blk * 256 + tid;
    int j = o & 7, cout = (o >> 3) & 127, k8 = (o >> 10) & 15, tap = o >> 14;
    wprep[o] = (__bf16)w[((size_t)tap * 128 + k8 * 8 + j) * 128 + cout];
  } else {
    if (tid < 128) {
      float s = gamma[tid] * rsqrtf(var[tid] + 1e-3f);
      scale[tid] = s;
      shift[tid] = (b[tid] - mean[tid]) * s + beta[tid];
    }
    for (int i = tid; i < NACT; i += 256) flags[active[i]] = 1;
  }
}

// Copy non-active 16x16 blocks x -> y. Zero LDS, full occupancy, nontemporal.
__global__ __launch_bounds__(256) void copy_kernel(const float* __restrict__ x,
                                                   const int* __restrict__ flags,
                                                   float* __restrict__ y) {
  int pb = blockIdx.x;
  if (flags[pb]) return;
  int bn = pb >> 8, by = (pb >> 4) & 15, bx = pb & 15;
  size_t base4 = ((((size_t)bn * H_ + by * 16) * W_ + bx * 16) * C_) >> 2;
  const f32x4* __restrict__ xs = (const f32x4*)x;
  f32x4* __restrict__ ys = (f32x4*)y;
#pragma unroll 4
  for (int i = 0; i < 32; ++i) {
    int lin = (i << 8) + threadIdx.x;
    int row = lin >> 9, rem = lin & 511;
    size_t idx4 = base4 + (size_t)row * (W_ * C_ / 4) + rem;
    f32x4 v = __builtin_nontemporal_load(&xs[idx4]);
    __builtin_nontemporal_store(v, &ys[idx4]);
  }
}

// One workgroup (4 waves) per active block. Implicit GEMM M=256, N=128, K=1152.
// A (patch) staged bf16 in LDS (two 64-ch halves, XOR-swizzled, 41.5 KB).
// B (weights) loaded per-fragment DIRECTLY from global (L1/L2-resident 288 KB,
// reused by all blocks) -> no ldsB, no per-K-step barriers: the 18-step inner
// loop is pure ds_read + global_load + MFMA, compiler-pipelined.
__global__ __launch_bounds__(256, 2) void conv_kernel(
    const float* __restrict__ x, const __bf16* __restrict__ wprep,
    const float* __restrict__ scale, const float* __restrict__ shift,
    const int* __restrict__ active, float* __restrict__ y) {
  __shared__ unsigned char ldsA[324 * 128];   // 18*18 spatial x 64ch bf16 (swizzled)

  const int tid = threadIdx.x;
  const int lane = tid & 63;
  const int wid = tid >> 6;
  const int aid = active[blockIdx.x];
  const int bn = aid >> 8;
  const int by = (aid >> 4) & 15;
  const int bx = aid & 15;
  const int h0 = by * 16, w0 = bx * 16;
  const float* xb = x + (size_t)bn * (H_ * W_ * C_);

  // per-lane BN constants (cout = nb*16 + (lane&15))
  float sc[8], sh[8];
  {
    int col = lane & 15;
#pragma unroll
    for (int nb = 0; nb < 8; ++nb) {
      sc[nb] = scale[nb * 16 + col];
      sh[nb] = shift[nb * 16 + col];
    }
  }

  f32x4 acc[4][8];
  f32x4 zero = {0.f, 0.f, 0.f, 0.f};
#pragma unroll
  for (int i = 0; i < 4; ++i)
#pragma unroll
    for (int j = 0; j < 8; ++j) acc[i][j] = zero;

  const bf16x8* __restrict__ wq = (const bf16x8*)wprep;  // 16B fragment units
  const int koff = (lane >> 4) * 16;   // 16B k-chunk within 32 channels
  // B-frag base (16B units): tile*512 + (lane>>4)*128 + (lane&15)
  const int sbl = ((lane >> 4) << 7) + (lane & 15);

  for (int half = 0; half < 2; ++half) {
    __syncthreads();   // all waves done reading ldsA (previous half)
    // stage 18x18 x 64ch patch as bf16, XOR-swizzled: byte ^= (pixel&7)<<4
    for (int chunk = tid; chunk < 324 * 8; chunk += 256) {
      int s = chunk >> 3, c8 = chunk & 7;
      int iy = s / 18, ix = s - iy * 18;
      int hs = h0 + iy, wsp = w0 + ix;
      float4 f0 = make_float4(0.f, 0.f, 0.f, 0.f), f1 = f0;
      if (hs < H_ && wsp < W_) {
        const float* p = xb + (size_t)(hs * W_ + wsp) * C_ + half * 64 + c8 * 8;
        f0 = *(const float4*)p;
        f1 = *(const float4*)(p + 4);
      }
      bf16x8 v;
      v[0] = (__bf16)f0.x; v[1] = (__bf16)f0.y; v[2] = (__bf16)f0.z; v[3] = (__bf16)f0.w;
      v[4] = (__bf16)f1.x; v[5] = (__bf16)f1.y; v[6] = (__bf16)f1.z; v[7] = (__bf16)f1.w;
      int lin = s * 128 + c8 * 16;
      *(bf16x8*)(&ldsA[lin ^ ((s & 7) << 4)]) = v;
    }
    __syncthreads();   // ldsA staged

    // 18 barrier-free K-steps of 32 channels (tap 0..8 x 32-ch chunk)
#pragma unroll 2
    for (int ks = 0; ks < 18; ++ks) {
      int tap = ks >> 1, kch = ks & 1;
      int dyv = tap / 3, dxv = tap - dyv * 3;
      int tile = tap * 4 + half * 2 + kch;

      bf16x8 a[4];
#pragma unroll
      for (int mi = 0; mi < 4; ++mi) {
        int srow = (wid * 4 + mi + dyv) * 18 + dxv + (lane & 15);
        int lin = srow * 128 + kch * 64 + koff;
        a[mi] = *(const bf16x8*)(&ldsA[lin ^ ((srow & 7) << 4)]);
      }
      bf16x8 bfr[8];
      int sb = tile * 512 + sbl;
#pragma unroll
      for (int nb = 0; nb < 8; ++nb)
        bfr[nb] = wq[sb + nb * 16];
#pragma unroll
      for (int mi = 0; mi < 4; ++mi)
#pragma unroll
        for (int nb = 0; nb < 8; ++nb)
          acc[mi][nb] = __builtin_amdgcn_mfma_f32_16x16x32_bf16(a[mi], bfr[nb], acc[mi][nb], 0, 0, 0);
    }
  }

  // epilogue: BN + ReLU + scatter. D frag: col=lane&15, row=(lane>>4)*4+reg
  const int colc = lane & 15;
  float* yb = y + (((size_t)bn * H_ + h0) * W_ + w0) * C_;
#pragma unroll
  for (int mi = 0; mi < 4; ++mi) {
    int oy = wid * 4 + mi;
#pragma unroll
    for (int r = 0; r < 4; ++r) {
      int ox = (lane >> 4) * 4 + r;
      float* yr = yb + ((size_t)oy * W_ + ox) * C_;
#pragma unroll
      for (int nb = 0; nb < 8; ++nb) {
        float v = acc[mi][nb][r] * sc[nb] + sh[nb];
        __builtin_nontemporal_store(fmaxf(v, 0.f), &yr[nb * 16 + colc]);
      }
    }
  }
}

extern "C" void kernel_launch(void* const* d_in, const int* in_sizes, int n_in,
                              void* d_out, int out_size, void* d_ws, size_t ws_size,
                              hipStream_t stream) {
  const float* x     = (const float*)d_in[0];
  const float* w     = (const float*)d_in[1];
  const float* b     = (const float*)d_in[2];
  const float* gamma = (const float*)d_in[3];
  const float* beta  = (const float*)d_in[4];
  const float* mean  = (const float*)d_in[5];
  const float* var   = (const float*)d_in[6];
  const int*   act   = (const int*)d_in[7];
  float* y = (float*)d_out;
  char* ws = (char*)d_ws;
  __bf16* wprep = (__bf16*)ws;
  float* scale = (float*)(ws + SCALE_OFF);
  float* shift = (float*)(ws + SHIFT_OFF);
  int* flags = (int*)(ws + FLAGS_OFF);

  (void)hipMemsetAsync(flags, 0, NBPOS * sizeof(int), stream);
  prep_kernel<<<dim3(577), dim3(256), 0, stream>>>(w, b, gamma, beta, mean, var, act,
                                                   wprep, scale, shift, flags);
  copy_kernel<<<dim3(NBPOS), dim3(256), 0, stream>>>(x, flags, y);
  conv_kernel<<<dim3(NACT), dim3(256), 0, stream>>>(x, wprep, scale, shift, act, y);
}

// Round 6
// 80.245 us; speedup vs baseline: 1.1675x; 1.1675x over previous
//
#include <hip/hip_runtime.h>
#include <hip/hip_bf16.h>

#define H_ 256
#define W_ 256
#define C_ 128
#define NBPOS 1024   // N * 16 * 16 block positions
#define NACT 512

typedef __bf16 bf16x8 __attribute__((ext_vector_type(8)));
typedef float f32x4 __attribute__((ext_vector_type(4)));

// workspace layout (bytes)
#define SCALE_OFF 294912
#define SHIFT_OFF 295424
#define INACT_OFF 295936

// Weight repack fp32 HWIO -> bf16 [tap][cin8][cout][8] (576 blocks exact)
__global__ void prep_w_kernel(const float* __restrict__ w, __bf16* __restrict__ wprep) {
  int o = blockIdx.x * 256 + threadIdx.x;
  int j = o & 7, cout = (o >> 3) & 127, k8 = (o >> 10) & 15, tap = o >> 14;
  wprep[o] = (__bf16)w[((size_t)tap * 128 + k8 * 8 + j) * 128 + cout];
}

// One block, 1024 threads: BN fold + inactive-block list via LDS bitmap.
__global__ void small_kernel(const float* __restrict__ b, const float* __restrict__ gamma,
                             const float* __restrict__ beta, const float* __restrict__ mean,
                             const float* __restrict__ var, const int* __restrict__ active,
                             float* __restrict__ scale, float* __restrict__ shift,
                             int* __restrict__ inact) {
  __shared__ unsigned mask[32];
  __shared__ int cnt;
  int tid = threadIdx.x;
  if (tid < 32) mask[tid] = 0u;
  if (tid == 0) cnt = 0;
  __syncthreads();
  if (tid < NACT) {
    int a = active[tid];
    atomicOr(&mask[a >> 5], 1u << (a & 31));
  }
  if (tid < 128) {
    float s = gamma[tid] * rsqrtf(var[tid] + 1e-3f);
    scale[tid] = s;
    shift[tid] = (b[tid] - mean[tid]) * s + beta[tid];
  }
  __syncthreads();
  if (!((mask[tid >> 5] >> (tid & 31)) & 1u)) {
    int p = atomicAdd(&cnt, 1);
    inact[p] = tid;   // order nondeterministic; coverage (each id once) is what matters
  }
}

// One workgroup per active block; ALSO streams one inactive block x->y through
// registers, interleaved into the K-loop so HBM copy traffic overlaps MFMA.
// A (patch): LDS, two 64-ch halves, XOR-swizzled. B (weights): LDS ping-pong,
// write-one-ahead from regs, ONE barrier per K-step.
__global__ __launch_bounds__(256, 2) void conv_kernel(
    const float* __restrict__ x, const __bf16* __restrict__ wprep,
    const float* __restrict__ scale, const float* __restrict__ shift,
    const int* __restrict__ active, const int* __restrict__ inact,
    float* __restrict__ y) {
  __shared__ unsigned char ldsA[324 * 128];   // 41.5 KB
  __shared__ unsigned char ldsB[2][8192];     // 16 KB

  const int tid = threadIdx.x;
  const int lane = tid & 63;
  const int wid = tid >> 6;
  const int aid = active[blockIdx.x];
  const int bn = aid >> 8, by = (aid >> 4) & 15, bx = aid & 15;
  const int h0 = by * 16, w0 = bx * 16;
  const float* xb = x + (size_t)bn * (H_ * W_ * C_);

  // paired inactive block for the fused copy
  const int cid = inact[blockIdx.x];
  const int cn = cid >> 8, cy = (cid >> 4) & 15, cx = cid & 15;
  const size_t cbase4 = ((((size_t)cn * H_ + cy * 16) * W_ + cx * 16) * C_) >> 2;
  const f32x4* __restrict__ xs = (const f32x4*)x;
  f32x4* __restrict__ ys = (f32x4*)y;
  f32x4 cbuf[4];
  auto cidx = [&](int c, int k) -> size_t {
    int lin = (c << 10) + (k << 8) + tid;            // 8 chunks x 4 x 256 = 8192 f32x4
    return cbase4 + (size_t)(lin >> 9) * (W_ * C_ / 4) + (lin & 511);
  };
  auto copy_load = [&](int c) {
#pragma unroll
    for (int k = 0; k < 4; ++k) cbuf[k] = __builtin_nontemporal_load(&xs[cidx(c, k)]);
  };
  auto copy_store = [&](int c) {
#pragma unroll
    for (int k = 0; k < 4; ++k) __builtin_nontemporal_store(cbuf[k], &ys[cidx(c, k)]);
  };

  // per-lane BN constants (cout = nb*16 + (lane&15))
  float sc[8], sh[8];
  {
    int col = lane & 15;
#pragma unroll
    for (int nb = 0; nb < 8; ++nb) {
      sc[nb] = scale[nb * 16 + col];
      sh[nb] = shift[nb * 16 + col];
    }
  }

  f32x4 acc[4][8];
  f32x4 zero = {0.f, 0.f, 0.f, 0.f};
#pragma unroll
  for (int i = 0; i < 4; ++i)
#pragma unroll
    for (int j = 0; j < 8; ++j) acc[i][j] = zero;

  const uint4* wp4 = (const uint4*)wprep;
  uint4 t0, t1;
  auto load_t = [&](int u) {                  // weight tile for flat K-step u
    int ks = u % 18, h = u / 18;
    int tile = ((ks >> 1) << 2) + (h << 1) + (ks & 1);
    t0 = wp4[tile * 512 + tid];
    t1 = wp4[tile * 512 + 256 + tid];
  };
  auto stage = [&](int half) {                // 18x18 x 64ch patch -> bf16 LDS, XOR-swizzled
    for (int chunk = tid; chunk < 324 * 8; chunk += 256) {
      int s = chunk >> 3, c8 = chunk & 7;
      int iy = s / 18, ix = s - iy * 18;
      int hs = h0 + iy, wsp = w0 + ix;
      float4 f0 = make_float4(0.f, 0.f, 0.f, 0.f), f1 = f0;
      if (hs < H_ && wsp < W_) {
        const float* p = xb + (size_t)(hs * W_ + wsp) * C_ + half * 64 + c8 * 8;
        f0 = *(const float4*)p;
        f1 = *(const float4*)(p + 4);
      }
      bf16x8 v;
      v[0] = (__bf16)f0.x; v[1] = (__bf16)f0.y; v[2] = (__bf16)f0.z; v[3] = (__bf16)f0.w;
      v[4] = (__bf16)f1.x; v[5] = (__bf16)f1.y; v[6] = (__bf16)f1.z; v[7] = (__bf16)f1.w;
      int lin = s * 128 + c8 * 16;
      *(bf16x8*)(&ldsA[lin ^ ((s & 7) << 4)]) = v;
    }
  };

  // prologue
  load_t(0);
  copy_load(0);                               // earliest HBM issue for the paired copy
  stage(0);
  ((uint4*)ldsB[0])[tid] = t0;
  ((uint4*)ldsB[0])[256 + tid] = t1;
  load_t(1);
  __syncthreads();

  const int koff = (lane >> 4) * 16;
  const int colb = (lane & 15) * 16;
  const int krow = (lane >> 4) * 2048;

  int cc = 0;
  for (int u = 0; u < 36; ++u) {
    // copy interleave at step top: store lands after ~5 steps of hiding,
    // next chunk's loads get a full step before the barrier drain.
    if (u == 5 || u == 10 || u == 15 || u == 19 || u == 24 || u == 28 || u == 33) {
      copy_store(cc);
      copy_load(cc + 1);
      ++cc;
    }
    int cur = u & 1;
    if (u < 35) {
      ((uint4*)ldsB[cur ^ 1])[tid] = t0;        // tile u+1
      ((uint4*)ldsB[cur ^ 1])[256 + tid] = t1;
      if (u < 34) load_t(u + 2);
    }
    int ks = u % 18;
    int tap = ks >> 1, kch = ks & 1;
    int dyv = tap / 3, dxv = tap - dyv * 3;

    bf16x8 a[4];
#pragma unroll
    for (int mi = 0; mi < 4; ++mi) {
      int srow = (wid * 4 + mi + dyv) * 18 + dxv + (lane & 15);
      int lin = srow * 128 + kch * 64 + koff;
      a[mi] = *(const bf16x8*)(&ldsA[lin ^ ((srow & 7) << 4)]);
    }
    bf16x8 bfr[8];
#pragma unroll
    for (int nb = 0; nb < 8; ++nb)
      bfr[nb] = *(const bf16x8*)(&ldsB[cur][krow + nb * 256 + colb]);
#pragma unroll
    for (int mi = 0; mi < 4; ++mi)
#pragma unroll
      for (int nb = 0; nb < 8; ++nb)
        acc[mi][nb] = __builtin_amdgcn_mfma_f32_16x16x32_bf16(a[mi], bfr[nb], acc[mi][nb], 0, 0, 0);

    __syncthreads();                            // ldsB[cur] reads done; u+1 writes visible
    if (u == 17) {                              // re-stage ldsA with channel half 1
      stage(1);
      __syncthreads();
    }
  }
  copy_store(7);

  // epilogue: BN + ReLU + scatter. D frag: col=lane&15, row=(lane>>4)*4+reg
  const int colc = lane & 15;
  float* yb = y + (((size_t)bn * H_ + h0) * W_ + w0) * C_;
#pragma unroll
  for (int mi = 0; mi < 4; ++mi) {
    int oy = wid * 4 + mi;
#pragma unroll
    for (int r = 0; r < 4; ++r) {
      int ox = (lane >> 4) * 4 + r;
      float* yr = yb + ((size_t)oy * W_ + ox) * C_;
#pragma unroll
      for (int nb = 0; nb < 8; ++nb) {
        float v = acc[mi][nb][r] * sc[nb] + sh[nb];
        __builtin_nontemporal_store(fmaxf(v, 0.f), &yr[nb * 16 + colc]);
      }
    }
  }
}

extern "C" void kernel_launch(void* const* d_in, const int* in_sizes, int n_in,
                              void* d_out, int out_size, void* d_ws, size_t ws_size,
                              hipStream_t stream) {
  const float* x     = (const float*)d_in[0];
  const float* w     = (const float*)d_in[1];
  const float* b     = (const float*)d_in[2];
  const float* gamma = (const float*)d_in[3];
  const float* beta  = (const float*)d_in[4];
  const float* mean  = (const float*)d_in[5];
  const float* var   = (const float*)d_in[6];
  const int*   act   = (const int*)d_in[7];
  float* y = (float*)d_out;
  char* ws = (char*)d_ws;
  __bf16* wprep = (__bf16*)ws;
  float* scale = (float*)(ws + SCALE_OFF);
  float* shift = (float*)(ws + SHIFT_OFF);
  int* inact = (int*)(ws + INACT_OFF);

  prep_w_kernel<<<dim3(576), dim3(256), 0, stream>>>(w, wprep);
  small_kernel<<<dim3(1), dim3(1024), 0, stream>>>(b, gamma, beta, mean, var, act,
                                                   scale, shift, inact);
  conv_kernel<<<dim3(NACT), dim3(256), 0, stream>>>(x, wprep, scale, shift, act, inact, y);
}

// Round 7
// 79.702 us; speedup vs baseline: 1.1754x; 1.0068x over previous
//
#include <hip/hip_runtime.h>
#include <hip/hip_bf16.h>

#define H_ 256
#define W_ 256
#define C_ 128
#define NBPOS 1024   // N * 16 * 16 block positions
#define NACT 512

typedef __bf16 bf16x8 __attribute__((ext_vector_type(8)));
typedef float f32x4 __attribute__((ext_vector_type(4)));

// workspace layout (bytes)
#define SCALE_OFF 294912
#define SHIFT_OFF 295424
#define FLAGS_OFF 295936

// Weight repack fp32 HWIO -> bf16 [tap][cin8][cout][8] (576 blocks exact)
__global__ void prep_w_kernel(const float* __restrict__ w, __bf16* __restrict__ wprep) {
  int o = blockIdx.x * 256 + threadIdx.x;
  int j = o & 7, cout = (o >> 3) & 127, k8 = (o >> 10) & 15, tap = o >> 14;
  wprep[o] = (__bf16)w[((size_t)tap * 128 + k8 * 8 + j) * 128 + cout];
}

// One block, 1024 threads: BN fold + full flags table via LDS bitmap.
__global__ void small_kernel(const float* __restrict__ b, const float* __restrict__ gamma,
                             const float* __restrict__ beta, const float* __restrict__ mean,
                             const float* __restrict__ var, const int* __restrict__ active,
                             float* __restrict__ scale, float* __restrict__ shift,
                             int* __restrict__ flags) {
  __shared__ unsigned mask[32];
  int tid = threadIdx.x;
  if (tid < 32) mask[tid] = 0u;
  __syncthreads();
  if (tid < NACT) {
    int a = active[tid];
    atomicOr(&mask[a >> 5], 1u << (a & 31));
  }
  if (tid < 128) {
    float s = gamma[tid] * rsqrtf(var[tid] + 1e-3f);
    scale[tid] = s;
    shift[tid] = (b[tid] - mean[tid]) * s + beta[tid];
  }
  __syncthreads();
  flags[tid] = (mask[tid >> 5] >> (tid & 31)) & 1u;
}

// Copy non-active 16x16 blocks x -> y. Plain x loads (keep L3 warm for conv),
// nontemporal y stores (y never re-read). Zero LDS -> full occupancy.
__global__ __launch_bounds__(256) void copy_kernel(const float* __restrict__ x,
                                                   const int* __restrict__ flags,
                                                   float* __restrict__ y) {
  int pb = blockIdx.x;
  if (flags[pb]) return;
  int bn = pb >> 8, by = (pb >> 4) & 15, bx = pb & 15;
  size_t base4 = ((((size_t)bn * H_ + by * 16) * W_ + bx * 16) * C_) >> 2;
  const f32x4* __restrict__ xs = (const f32x4*)x;
  f32x4* __restrict__ ys = (f32x4*)y;
#pragma unroll 4
  for (int i = 0; i < 32; ++i) {
    int lin = (i << 8) + threadIdx.x;
    int row = lin >> 9, rem = lin & 511;
    size_t idx4 = base4 + (size_t)row * (W_ * C_ / 4) + rem;
    f32x4 v = xs[idx4];
    __builtin_nontemporal_store(v, &ys[idx4]);
  }
}

// 1024 workgroups = (active block) x (spatial half mh). Each: M=128 (8 output
// rows x 16 cols), N=128 cout, K=1152. Patch tile = 10 rows x 18 cols x 64ch
// bf16 in LDS (22.5 KB, XOR-swizzled); B = ldsB ping-pong (16 KB), ONE barrier
// per K-step. 39.4 KB LDS -> 4 wgs/CU = 16 waves/CU for latency hiding.
__global__ __launch_bounds__(256, 4) void conv_kernel(
    const float* __restrict__ x, const __bf16* __restrict__ wprep,
    const float* __restrict__ scale, const float* __restrict__ shift,
    const int* __restrict__ active, float* __restrict__ y) {
  __shared__ unsigned char ldsA[180 * 128];   // 10*18 px x 64ch bf16 = 23040 B
  __shared__ unsigned char ldsB[2][8192];     // ping-pong 32k x 128cout bf16

  const int tid = threadIdx.x;
  const int lane = tid & 63;
  const int wid = tid >> 6;
  const int aid = active[blockIdx.x >> 1];
  const int mh = blockIdx.x & 1;              // spatial half: rows 0-7 or 8-15
  const int bn = aid >> 8, by = (aid >> 4) & 15, bx = aid & 15;
  const int h0 = by * 16, w0 = bx * 16;
  const int hm = h0 + mh * 8;                 // this wg's patch-row origin
  const float* xb = x + (size_t)bn * (H_ * W_ * C_);

  f32x4 acc[2][8];
  f32x4 zero = {0.f, 0.f, 0.f, 0.f};
#pragma unroll
  for (int i = 0; i < 2; ++i)
#pragma unroll
    for (int j = 0; j < 8; ++j) acc[i][j] = zero;

  const uint4* wp4 = (const uint4*)wprep;
  uint4 t0, t1;
  auto load_t = [&](int u) {                  // weight tile for flat K-step u
    int ks = u % 18, h = u / 18;
    int tile = ((ks >> 1) << 2) + (h << 1) + (ks & 1);
    t0 = wp4[tile * 512 + tid];
    t1 = wp4[tile * 512 + 256 + tid];
  };
  auto stage = [&](int half) {                // 10x18 px x 64ch -> bf16 LDS, XOR-swizzled
    for (int u = tid; u < 180 * 8; u += 256) {
      int s = u >> 3, c8 = u & 7;             // s = pr*18 + col
      int pr = s / 18, col = s - pr * 18;
      int hs = hm + pr, wsp = w0 + col;
      float4 f0 = make_float4(0.f, 0.f, 0.f, 0.f), f1 = f0;
      if (hs < H_ && wsp < W_) {
        const float* p = xb + (size_t)(hs * W_ + wsp) * C_ + half * 64 + c8 * 8;
        f0 = *(const float4*)p;
        f1 = *(const float4*)(p + 4);
      }
      bf16x8 v;
      v[0] = (__bf16)f0.x; v[1] = (__bf16)f0.y; v[2] = (__bf16)f0.z; v[3] = (__bf16)f0.w;
      v[4] = (__bf16)f1.x; v[5] = (__bf16)f1.y; v[6] = (__bf16)f1.z; v[7] = (__bf16)f1.w;
      int lin = s * 128 + c8 * 16;
      *(bf16x8*)(&ldsA[lin ^ ((s & 7) << 4)]) = v;
    }
  };

  // prologue
  load_t(0);
  stage(0);
  ((uint4*)ldsB[0])[tid] = t0;
  ((uint4*)ldsB[0])[256 + tid] = t1;
  load_t(1);
  __syncthreads();

  const int koff = (lane >> 4) * 16;          // 16B k-chunk within 32 channels
  const int colb = (lane & 15) * 16;
  const int krow = (lane >> 4) * 2048;

  for (int u = 0; u < 36; ++u) {
    int cur = u & 1;
    if (u < 35) {
      ((uint4*)ldsB[cur ^ 1])[tid] = t0;      // tile u+1
      ((uint4*)ldsB[cur ^ 1])[256 + tid] = t1;
      if (u < 34) load_t(u + 2);
    }
    int ks = u % 18;
    int tap = ks >> 1, kch = ks & 1;
    int dyv = tap / 3, dxv = tap - dyv * 3;

    bf16x8 a[2];
#pragma unroll
    for (int mi = 0; mi < 2; ++mi) {
      int srow = (wid * 2 + mi + dyv) * 18 + dxv + (lane & 15);
      int lin = srow * 128 + kch * 64 + koff;
      a[mi] = *(const bf16x8*)(&ldsA[lin ^ ((srow & 7) << 4)]);
    }
    bf16x8 bfr[8];
#pragma unroll
    for (int nb = 0; nb < 8; ++nb)
      bfr[nb] = *(const bf16x8*)(&ldsB[cur][krow + nb * 256 + colb]);
#pragma unroll
    for (int mi = 0; mi < 2; ++mi)
#pragma unroll
      for (int nb = 0; nb < 8; ++nb)
        acc[mi][nb] = __builtin_amdgcn_mfma_f32_16x16x32_bf16(a[mi], bfr[nb], acc[mi][nb], 0, 0, 0);

    __syncthreads();                          // ldsB[cur] reads done; u+1 writes visible
    if (u == 17) {                            // re-stage ldsA with channel half 1
      stage(1);
      __syncthreads();
    }
  }

  // epilogue: BN + ReLU + scatter. D frag: col=lane&15, row=(lane>>4)*4+reg
  const int colc = lane & 15;
  float sc[8], sh[8];
#pragma unroll
  for (int nb = 0; nb < 8; ++nb) {
    sc[nb] = scale[nb * 16 + colc];
    sh[nb] = shift[nb * 16 + colc];
  }
  float* yb = y + (((size_t)bn * H_ + hm) * W_ + w0) * C_;
#pragma unroll
  for (int mi = 0; mi < 2; ++mi) {
    int oy = wid * 2 + mi;                    // row within this wg's 8-row half
#pragma unroll
    for (int r = 0; r < 4; ++r) {
      int ox = (lane >> 4) * 4 + r;
      float* yr = yb + ((size_t)oy * W_ + ox) * C_;
#pragma unroll
      for (int nb = 0; nb < 8; ++nb) {
        float v = acc[mi][nb][r] * sc[nb] + sh[nb];
        __builtin_nontemporal_store(fmaxf(v, 0.f), &yr[nb * 16 + colc]);
      }
    }
  }
}

extern "C" void kernel_launch(void* const* d_in, const int* in_sizes, int n_in,
                              void* d_out, int out_size, void* d_ws, size_t ws_size,
                              hipStream_t stream) {
  const float* x     = (const float*)d_in[0];
  const float* w     = (const float*)d_in[1];
  const float* b     = (const float*)d_in[2];
  const float* gamma = (const float*)d_in[3];
  const float* beta  = (const float*)d_in[4];
  const float* mean  = (const float*)d_in[5];
  const float* var   = (const float*)d_in[6];
  const int*   act   = (const int*)d_in[7];
  float* y = (float*)d_out;
  char* ws = (char*)d_ws;
  __bf16* wprep = (__bf16*)ws;
  float* scale = (float*)(ws + SCALE_OFF);
  float* shift = (float*)(ws + SHIFT_OFF);
  int* flags = (int*)(ws + FLAGS_OFF);

  prep_w_kernel<<<dim3(576), dim3(256), 0, stream>>>(w, wprep);
  small_kernel<<<dim3(1), dim3(1024), 0, stream>>>(b, gamma, beta, mean, var, act,
                                                   scale, shift, flags);
  copy_kernel<<<dim3(NBPOS), dim3(256), 0, stream>>>(x, flags, y);
  conv_kernel<<<dim3(NACT * 2), dim3(256), 0, stream>>>(x, wprep, scale, shift, act, y);
}

// Round 8
// 75.259 us; speedup vs baseline: 1.2448x; 1.0590x over previous
//
#include <hip/hip_runtime.h>
#include <hip/hip_bf16.h>

#define H_ 256
#define W_ 256
#define C_ 128
#define NBPOS 1024   // N * 16 * 16 block positions
#define NACT 512

typedef __bf16 bf16x8 __attribute__((ext_vector_type(8)));
typedef float f32x4 __attribute__((ext_vector_type(4)));

// workspace layout (bytes)
#define SCALE_OFF 294912
#define SHIFT_OFF 295424
#define INACT_OFF 295936

// Blocks 0..575: weight repack fp32 HWIO -> bf16 [tap][cin8][cout][8].
// Block 576: BN fold + inactive-block list (bitmap + compaction).
__global__ void prep_kernel(const float* __restrict__ w, const float* __restrict__ b,
                            const float* __restrict__ gamma, const float* __restrict__ beta,
                            const float* __restrict__ mean, const float* __restrict__ var,
                            const int* __restrict__ active,
                            __bf16* __restrict__ wprep, float* __restrict__ scale,
                            float* __restrict__ shift, int* __restrict__ inact) {
  int blk = blockIdx.x, tid = threadIdx.x;
  if (blk < 576) {
    int o = blk * 256 + tid;
    int j = o & 7, cout = (o >> 3) & 127, k8 = (o >> 10) & 15, tap = o >> 14;
    wprep[o] = (__bf16)w[((size_t)tap * 128 + k8 * 8 + j) * 128 + cout];
    return;
  }
  __shared__ unsigned mask[32];
  __shared__ int cnt;
  if (tid < 32) mask[tid] = 0u;
  if (tid == 0) cnt = 0;
  __syncthreads();
  for (int i = tid; i < NACT; i += 256) {
    int a = active[i];
    atomicOr(&mask[a >> 5], 1u << (a & 31));
  }
  if (tid < 128) {
    float s = gamma[tid] * rsqrtf(var[tid] + 1e-3f);
    scale[tid] = s;
    shift[tid] = (b[tid] - mean[tid]) * s + beta[tid];
  }
  __syncthreads();
  for (int p = tid; p < NBPOS; p += 256) {
    if (!((mask[p >> 5] >> (p & 31)) & 1u)) {
      int q = atomicAdd(&cnt, 1);
      inact[q] = p;   // order nondeterministic; disjoint coverage is what matters
    }
  }
}

// ONE main kernel, 1536 wgs interleaved 2 conv : 1 copy so every CU holds a mix
// of MFMA work and HBM-streaming work concurrently.
//   idx%3==2 -> copy wg: stream inactive block inact[idx/3] x->y, early return
//               (no barriers, plain loads keep x in L3, NT stores for y).
//   else     -> conv wg j=(idx/3)*2+(idx%3) in 0..1023: half-block M=128 tile
//               of active[j>>1] (rows (j&1)*8..+8), K=1152 implicit GEMM.
// Conv: A patch 10x18px x 64ch bf16 LDS (XOR-swizzled), B ldsB ping-pong with
// write-one-ahead, ONE barrier per K-step. 39.4 KB LDS, <=128 VGPR -> 4 wg/CU.
__global__ __launch_bounds__(256, 4) void main_kernel(
    const float* __restrict__ x, const __bf16* __restrict__ wprep,
    const float* __restrict__ scale, const float* __restrict__ shift,
    const int* __restrict__ active, const int* __restrict__ inact,
    float* __restrict__ y) {
  __shared__ unsigned char ldsA[180 * 128];   // 10*18 px x 64ch bf16 = 23040 B
  __shared__ unsigned char ldsB[2][8192];     // ping-pong 32k x 128cout bf16

  const int idx = blockIdx.x;
  const int tid = threadIdx.x;

  if (idx % 3 == 2) {
    // ---- copy path ----
    const int cid = inact[idx / 3];
    const int cn = cid >> 8, cy = (cid >> 4) & 15, cx = cid & 15;
    const size_t base4 = ((((size_t)cn * H_ + cy * 16) * W_ + cx * 16) * C_) >> 2;
    const f32x4* __restrict__ xs = (const f32x4*)x;
    f32x4* __restrict__ ys = (f32x4*)y;
#pragma unroll 4
    for (int i = 0; i < 32; ++i) {
      int lin = (i << 8) + tid;
      int row = lin >> 9, rem = lin & 511;
      size_t idx4 = base4 + (size_t)row * (W_ * C_ / 4) + rem;
      f32x4 v = xs[idx4];
      __builtin_nontemporal_store(v, &ys[idx4]);
    }
    return;
  }

  // ---- conv path ----
  const int j = (idx / 3) * 2 + (idx % 3);    // 0..1023
  const int lane = tid & 63;
  const int wid = tid >> 6;
  const int aid = active[j >> 1];
  const int mh = j & 1;                       // spatial half: rows 0-7 or 8-15
  const int bn = aid >> 8, by = (aid >> 4) & 15, bx = aid & 15;
  const int h0 = by * 16, w0 = bx * 16;
  const int hm = h0 + mh * 8;
  const float* xb = x + (size_t)bn * (H_ * W_ * C_);

  f32x4 acc[2][8];
  f32x4 zero = {0.f, 0.f, 0.f, 0.f};
#pragma unroll
  for (int i = 0; i < 2; ++i)
#pragma unroll
    for (int jj = 0; jj < 8; ++jj) acc[i][jj] = zero;

  const uint4* wp4 = (const uint4*)wprep;
  uint4 t0, t1;
  auto load_t = [&](int u) {                  // weight tile for flat K-step u
    int ks = u % 18, h = u / 18;
    int tile = ((ks >> 1) << 2) + (h << 1) + (ks & 1);
    t0 = wp4[tile * 512 + tid];
    t1 = wp4[tile * 512 + 256 + tid];
  };
  auto stage = [&](int half) {                // 10x18 px x 64ch -> bf16 LDS, XOR-swizzled
    for (int u = tid; u < 180 * 8; u += 256) {
      int s = u >> 3, c8 = u & 7;             // s = pr*18 + col
      int pr = s / 18, col = s - pr * 18;
      int hs = hm + pr, wsp = w0 + col;
      float4 f0 = make_float4(0.f, 0.f, 0.f, 0.f), f1 = f0;
      if (hs < H_ && wsp < W_) {
        const float* p = xb + (size_t)(hs * W_ + wsp) * C_ + half * 64 + c8 * 8;
        f0 = *(const float4*)p;
        f1 = *(const float4*)(p + 4);
      }
      bf16x8 v;
      v[0] = (__bf16)f0.x; v[1] = (__bf16)f0.y; v[2] = (__bf16)f0.z; v[3] = (__bf16)f0.w;
      v[4] = (__bf16)f1.x; v[5] = (__bf16)f1.y; v[6] = (__bf16)f1.z; v[7] = (__bf16)f1.w;
      int lin = s * 128 + c8 * 16;
      *(bf16x8*)(&ldsA[lin ^ ((s & 7) << 4)]) = v;
    }
  };

  // prologue
  load_t(0);
  stage(0);
  ((uint4*)ldsB[0])[tid] = t0;
  ((uint4*)ldsB[0])[256 + tid] = t1;
  load_t(1);
  __syncthreads();

  const int koff = (lane >> 4) * 16;          // 16B k-chunk within 32 channels
  const int colb = (lane & 15) * 16;
  const int krow = (lane >> 4) * 2048;

  for (int u = 0; u < 36; ++u) {
    int cur = u & 1;
    if (u < 35) {
      ((uint4*)ldsB[cur ^ 1])[tid] = t0;      // tile u+1
      ((uint4*)ldsB[cur ^ 1])[256 + tid] = t1;
      if (u < 34) load_t(u + 2);
    }
    int ks = u % 18;
    int tap = ks >> 1, kch = ks & 1;
    int dyv = tap / 3, dxv = tap - dyv * 3;

    bf16x8 a[2];
#pragma unroll
    for (int mi = 0; mi < 2; ++mi) {
      int srow = (wid * 2 + mi + dyv) * 18 + dxv + (lane & 15);
      int lin = srow * 128 + kch * 64 + koff;
      a[mi] = *(const bf16x8*)(&ldsA[lin ^ ((srow & 7) << 4)]);
    }
    bf16x8 bfr[8];
#pragma unroll
    for (int nb = 0; nb < 8; ++nb)
      bfr[nb] = *(const bf16x8*)(&ldsB[cur][krow + nb * 256 + colb]);
#pragma unroll
    for (int mi = 0; mi < 2; ++mi)
#pragma unroll
      for (int nb = 0; nb < 8; ++nb)
        acc[mi][nb] = __builtin_amdgcn_mfma_f32_16x16x32_bf16(a[mi], bfr[nb], acc[mi][nb], 0, 0, 0);

    __syncthreads();                          // ldsB[cur] reads done; u+1 writes visible
    if (u == 17) {                            // re-stage ldsA with channel half 1
      stage(1);
      __syncthreads();
    }
  }

  // epilogue: BN + ReLU + scatter. D frag: col=lane&15, row=(lane>>4)*4+reg
  const int colc = lane & 15;
  float sc[8], sh[8];
#pragma unroll
  for (int nb = 0; nb < 8; ++nb) {
    sc[nb] = scale[nb * 16 + colc];
    sh[nb] = shift[nb * 16 + colc];
  }
  float* yb = y + (((size_t)bn * H_ + hm) * W_ + w0) * C_;
#pragma unroll
  for (int mi = 0; mi < 2; ++mi) {
    int oy = wid * 2 + mi;                    // row within this wg's 8-row half
#pragma unroll
    for (int r = 0; r < 4; ++r) {
      int ox = (lane >> 4) * 4 + r;
      float* yr = yb + ((size_t)oy * W_ + ox) * C_;
#pragma unroll
      for (int nb = 0; nb < 8; ++nb) {
        float v = acc[mi][nb][r] * sc[nb] + sh[nb];
        __builtin_nontemporal_store(fmaxf(v, 0.f), &yr[nb * 16 + colc]);
      }
    }
  }
}

extern "C" void kernel_launch(void* const* d_in, const int* in_sizes, int n_in,
                              void* d_out, int out_size, void* d_ws, size_t ws_size,
                              hipStream_t stream) {
  const float* x     = (const float*)d_in[0];
  const float* w     = (const float*)d_in[1];
  const float* b     = (const float*)d_in[2];
  const float* gamma = (const float*)d_in[3];
  const float* beta  = (const float*)d_in[4];
  const float* mean  = (const float*)d_in[5];
  const float* var   = (const float*)d_in[6];
  const int*   act   = (const int*)d_in[7];
  float* y = (float*)d_out;
  char* ws = (char*)d_ws;
  __bf16* wprep = (__bf16*)ws;
  float* scale = (float*)(ws + SCALE_OFF);
  float* shift = (float*)(ws + SHIFT_OFF);
  int* inact = (int*)(ws + INACT_OFF);

  prep_kernel<<<dim3(577), dim3(256), 0, stream>>>(w, b, gamma, beta, mean, var, act,
                                                   wprep, scale, shift, inact);
  main_kernel<<<dim3(1536), dim3(256), 0, stream>>>(x, wprep, scale, shift, act, inact, y);
}